// Round 2
// baseline (285.532 us; speedup 1.0000x reference)
//
#include <hip/hip_runtime.h>
#include <hip/hip_bf16.h>

typedef unsigned short u16;
typedef __attribute__((ext_vector_type(8))) __bf16 bf8v;
typedef __attribute__((ext_vector_type(4))) float f32x4;
typedef __attribute__((ext_vector_type(4))) unsigned uint4v;

#define B_ 4
#define N_ 16384
#define M_ 16384
#define K_ 16
#define C_ 64
#define O_ 64
#define G_ 8

__device__ __forceinline__ float bf2f(u16 x){
  union { unsigned u; float f; } v; v.u = ((unsigned)x) << 16; return v.f;
}
__device__ __forceinline__ u16 f2bf(float f){
  union { float f; unsigned u; } v; v.f = f;
  unsigned u = v.u;
  return (u16)((u + 0x7FFFu + ((u >> 16) & 1u)) >> 16);
}
__device__ __forceinline__ uint4v pack8(const float* v){
  unsigned pk[4];
  #pragma unroll
  for (int jj=0;jj<4;jj++){
    u16 lo = f2bf(v[jj*2]); u16 hi = f2bf(v[jj*2+1]);
    pk[jj] = (unsigned)lo | ((unsigned)hi<<16);
  }
  uint4v r = {pk[0],pk[1],pk[2],pk[3]};
  return r;
}

// ---------------------------------------------------------------------------
// Kernel 1: precompute (f32 inputs -> bf16 workspace)
//   blocks [0,256):   xk[b,n,o] = fea^T@Wk + bk,  xv = fea^T@Wv + bv
//   blocks [256,512): qc[b,m,o] = cpr - x_q
// ---------------------------------------------------------------------------
__global__ __launch_bounds__(256) void pre_kernel(
    const float* __restrict__ center_pos, const float* __restrict__ center_fea,
    const float* __restrict__ fea,
    const float* __restrict__ Wq, const float* __restrict__ bq,
    const float* __restrict__ Wk, const float* __restrict__ bk,
    const float* __restrict__ Wv, const float* __restrict__ bv,
    const float* __restrict__ cpe_w1, const float* __restrict__ cpe_s, const float* __restrict__ cpe_b,
    const float* __restrict__ cpe_w2, const float* __restrict__ cpe_b2,
    u16* __restrict__ xk, u16* __restrict__ xv, u16* __restrict__ qc)
{
  int tid = threadIdx.x;
  int blk = blockIdx.x;
  __shared__ float sA[64*64];
  __shared__ float sB[64*64];
  __shared__ float sE[256];   // folded cpe_w1*s (192) + cpe_b (64)
  __shared__ float sF[128];   // kv: bk|bv ; qc: init = cpe_b2 - bq

  if (blk < 256) {
    // ---- x_k / x_v path ----
    for (int e = tid; e < 4096; e += 256){ sA[e] = Wk[e]; sB[e] = Wv[e]; }
    if (tid < 64){ sF[tid] = bk[tid]; sF[64+tid] = bv[tid]; }
    __syncthreads();
    int p = blk*256 + tid;               // 0 .. B*N-1
    int b = p >> 14, n = p & (N_-1);
    const float* fptr = fea + (long)b*C_*N_ + n;
    float ak[64], av[64];
    #pragma unroll
    for (int o=0;o<64;o++){ ak[o]=0.f; av[o]=0.f; }
    #pragma unroll 1
    for (int c=0;c<64;c++){
      float f = fptr[(long)c*N_];
      const f32x4* wk4 = (const f32x4*)&sA[c*64];
      const f32x4* wv4 = (const f32x4*)&sB[c*64];
      #pragma unroll
      for (int o4=0;o4<16;o4++){
        f32x4 a = wk4[o4], v = wv4[o4];
        #pragma unroll
        for (int j=0;j<4;j++){ ak[o4*4+j] += f*a[j]; av[o4*4+j] += f*v[j]; }
      }
    }
    #pragma unroll
    for (int o=0;o<64;o++){ ak[o] += sF[o]; av[o] += sF[64+o]; }
    long obase = (long)p*64;
    #pragma unroll
    for (int oc=0;oc<64;oc+=8){
      *(uint4v*)(xk + obase + oc) = pack8(&ak[oc]);
      *(uint4v*)(xv + obase + oc) = pack8(&av[oc]);
    }
  } else {
    // ---- qc = cpr - x_q path ----
    for (int e = tid; e < 4096; e += 256){ sA[e] = Wq[e]; sB[e] = cpe_w2[e]; }
    if (tid < 64){
      float sc = cpe_s[tid];
      sE[tid]      = cpe_w1[tid]*sc;
      sE[64+tid]   = cpe_w1[64+tid]*sc;
      sE[128+tid]  = cpe_w1[128+tid]*sc;
      sE[192+tid]  = cpe_b[tid];
      sF[tid]      = cpe_b2[tid] - bq[tid];
    }
    __syncthreads();
    int p = (blk-256)*256 + tid;         // 0 .. B*M-1
    int b = p >> 14, m = p & (M_-1);
    const float* cfptr = center_fea + (long)b*C_*M_ + m;
    long c3 = (long)p*3;
    float cp0 = center_pos[c3], cp1 = center_pos[c3+1], cp2 = center_pos[c3+2];
    float acc[64];
    #pragma unroll
    for (int o=0;o<64;o++) acc[o] = sF[o];
    #pragma unroll 1
    for (int c=0;c<64;c++){
      float f  = cfptr[(long)c*M_];
      float hc = fmaxf(cp0*sE[c] + cp1*sE[64+c] + cp2*sE[128+c] + sE[192+c], 0.f);
      const f32x4* wq4 = (const f32x4*)&sA[c*64];
      const f32x4* w24 = (const f32x4*)&sB[c*64];
      #pragma unroll
      for (int o4=0;o4<16;o4++){
        f32x4 a = wq4[o4], w2v = w24[o4];
        #pragma unroll
        for (int j=0;j<4;j++) acc[o4*4+j] += hc*w2v[j] - f*a[j];
      }
    }
    long obase = (long)p*64;
    #pragma unroll
    for (int oc=0;oc<64;oc+=8)
      *(uint4v*)(qc + obase + oc) = pack8(&acc[oc]);
  }
}

// ---------------------------------------------------------------------------
// Kernel 2: main attention. 1 wave = 1 m-point (8 points/wave, 32/block).
// MFMA 16x16x32 bf16: A lane layout A[m=l&15][k=(l>>4)*8+j],
//                     B lane layout B[k=(l>>4)*8+j][n=l&15],
//                     C/D: row=(l>>4)*4+reg, col=l&15 (measured m89).
// ---------------------------------------------------------------------------
__global__ __launch_bounds__(256) void attn_kernel(
    const float* __restrict__ center_pos, const float* __restrict__ pos,
    const int* __restrict__ idx,
    const float* __restrict__ pe_w1, const float* __restrict__ pe_s, const float* __restrict__ pe_b,
    const float* __restrict__ pe_w2, const float* __restrict__ pe_b2,
    const float* __restrict__ we_w1, const float* __restrict__ we_s, const float* __restrict__ we_b,
    const float* __restrict__ we_w2, const float* __restrict__ we_b2,
    const u16* __restrict__ xk, const u16* __restrict__ xv, const u16* __restrict__ qc,
    float* __restrict__ out)
{
  int tid = threadIdx.x;
  __shared__ float s_w1f[192];     // pe_w1 * pe_s folded
  __shared__ float s_pb[64];       // pe_b
  __shared__ float s_ww1[512];     // we_w1 [64][8] f32
  __shared__ float s_ws[8], s_wb[8], s_wb2[8];
  __shared__ float s_ww2[64];      // we_w2 [8][8]
  __shared__ float s_pb2[64];      // pe_b2
  __shared__ float s_tile[32*66];  // out tile [pt][o], padded

  if (tid < 64){
    float sc = pe_s[tid];
    s_w1f[tid]     = pe_w1[tid]*sc;
    s_w1f[64+tid]  = pe_w1[64+tid]*sc;
    s_w1f[128+tid] = pe_w1[128+tid]*sc;
    s_pb[tid]  = pe_b[tid];
    s_pb2[tid] = pe_b2[tid];
    s_ww2[tid] = we_w2[tid];
  }
  if (tid >= 64 && tid < 72){
    int g = tid-64;
    s_ws[g]=we_s[g]; s_wb[g]=we_b[g]; s_wb2[g]=we_b2[g];
  }
  for (int e = tid; e < 512; e += 256) s_ww1[e] = we_w1[e];
  __syncthreads();

  int w = tid >> 6, l = tid & 63, c = l & 15, q = l >> 4, c8 = c & 7, qb = l & 48;

  // static B-fragments (registers)
  bf8v pw2f[4][2], ww1f[2];
  {
    union { bf8v v; u16 s[8]; } u_;
    #pragma unroll
    for (int t=0;t<4;t++)
      #pragma unroll
      for (int ks=0;ks<2;ks++){
        #pragma unroll
        for (int j=0;j<8;j++) u_.s[j] = f2bf(pe_w2[(ks*32 + q*8 + j)*64 + t*16 + c]);
        pw2f[t][ks] = u_.v;
      }
    #pragma unroll
    for (int ks=0;ks<2;ks++){
      #pragma unroll
      for (int j=0;j<8;j++) u_.s[j] = (c < 8) ? f2bf(we_w1[(ks*32 + q*8 + j)*8 + c]) : (u16)0;
      ww1f[ks] = u_.v;
    }
  }
  float ws_c = s_ws[c8], wb_c = s_wb[c8], wb2_c = s_wb2[c8];
  float w2col[8];
  #pragma unroll
  for (int g=0; g<8; g++) w2col[g] = s_ww2[g*8 + c8];
  float pb2t[4];
  #pragma unroll
  for (int t=0;t<4;t++) pb2t[t] = s_pb2[t*16 + c];

  int pbase = blockIdx.x * 32;
  int b = pbase >> 14;
  long xkb = (long)b * N_ * 64;

  #pragma unroll 1
  for (int i = 0; i < 8; i++){
    int p = pbase + w*8 + i;
    int iv = idx[(long)p*16 + c];       // neighbor index for A-row (l&15)
    long c3 = (long)p * 3;
    float cp0 = center_pos[c3], cp1 = center_pos[c3+1], cp2 = center_pos[c3+2];
    long pr3 = ((long)b * N_ + iv) * 3;
    float np0 = pos[pr3]   - cp0;
    float np1 = pos[pr3+1] - cp1;
    float np2 = pos[pr3+2] - cp2;

    // H1 = relu(npos @ pe_w1 * s + b), built directly as A-fragments
    bf8v h1f[2];
    {
      union { bf8v v; u16 s[8]; } hu;
      #pragma unroll
      for (int ks=0;ks<2;ks++){
        #pragma unroll
        for (int j=0;j<8;j++){
          int o = ks*32 + q*8 + j;
          float hv = np0*s_w1f[o] + np1*s_w1f[64+o] + np2*s_w1f[128+o] + s_pb[o];
          hu.s[j] = f2bf(fmaxf(hv, 0.f));
        }
        h1f[ks] = hu.v;
      }
    }

    // gathered x_k row, already A-fragment shaped
    const u16* krow = xk + xkb + (long)iv * 64;
    bf8v ka0 = *(const bf8v*)(krow + q*8);
    bf8v ka1 = *(const bf8v*)(krow + 32 + q*8);

    // qw[g] = qc[p,:] @ we_w1[:,g]  (folds RQK = NK + qc before the relu)
    const u16* qrow = qc + (long)p * 64;
    float qp = 0.f;
    #pragma unroll
    for (int ks=0;ks<2;ks++){
      #pragma unroll
      for (int j=0;j<8;j++){
        int o = ks*32 + q*8 + j;
        qp += bf2f(qrow[o]) * s_ww1[o*8 + c8];
      }
    }
    qp += __shfl_xor(qp, 16, 64);
    qp += __shfl_xor(qp, 32, 64);

    f32x4 h2a = {qp, qp, qp, qp};
    h2a = __builtin_amdgcn_mfma_f32_16x16x32_bf16(ka0, ww1f[0], h2a, 0, 0, 0);
    h2a = __builtin_amdgcn_mfma_f32_16x16x32_bf16(ka1, ww1f[1], h2a, 0, 0, 0);

    f32x4 prA[4];
    #pragma unroll
    for (int t=0;t<4;t++){
      f32x4 z = {0.f,0.f,0.f,0.f};
      z = __builtin_amdgcn_mfma_f32_16x16x32_bf16(h1f[0], pw2f[t][0], z, 0, 0, 0);
      z = __builtin_amdgcn_mfma_f32_16x16x32_bf16(h1f[1], pw2f[t][1], z, 0, 0, 0);
      prA[t] = z;
    }

    // weight-encode MLP tail + softmax over the 16 neighbors
    float h2r[4];
    #pragma unroll
    for (int r=0;r<4;r++) h2r[r] = fmaxf(h2a[r]*ws_c + wb_c, 0.f);
    float wl[4] = {wb2_c, wb2_c, wb2_c, wb2_c};
    #pragma unroll
    for (int g=0; g<8; g++){
      float wg = w2col[g];
      #pragma unroll
      for (int r=0;r<4;r++)
        wl[r] += __shfl(h2r[r], qb | g, 64) * wg;
    }
    float mx = fmaxf(fmaxf(wl[0],wl[1]), fmaxf(wl[2],wl[3]));
    mx = fmaxf(mx, __shfl_xor(mx, 16, 64));
    mx = fmaxf(mx, __shfl_xor(mx, 32, 64));
    float e[4];
    #pragma unroll
    for (int r=0;r<4;r++) e[r] = exp2f((wl[r]-mx)*1.44269504f);
    float sm = e[0]+e[1]+e[2]+e[3];
    sm += __shfl_xor(sm, 16, 64);
    sm += __shfl_xor(sm, 32, 64);
    float rn = 1.0f / sm;
    #pragma unroll
    for (int r=0;r<4;r++) e[r] *= rn;          // e[r] = W[q*4+r][c]

    // out[o] = sum_k (nv + pr)[k][o] * W[k][o>>3]   (pe_b2 folded via sum(W)=1)
    float ov[4] = {0.f,0.f,0.f,0.f};
    int ch = c >> 3;
    const u16* xvb = xv + xkb;
    #pragma unroll
    for (int r=0;r<4;r++){
      int ivr = __shfl(iv, (qb >> 2) | r, 64);  // idx[q*4+r]
      const u16* vrow = xvb + (long)ivr * 64;
      #pragma unroll
      for (int t=0;t<4;t++){
        float wv_ = __shfl(e[r], qb | (t*2 + ch), 64);
        float nv = bf2f(vrow[t*16 + c]);
        ov[t] += (prA[t][r] + nv) * wv_;
      }
    }
    #pragma unroll
    for (int t=0;t<4;t++){
      ov[t] += __shfl_xor(ov[t], 16, 64);
      ov[t] += __shfl_xor(ov[t], 32, 64);
      ov[t] += pb2t[t];
    }
    float selv = ov[0];
    selv = (q==1) ? ov[1] : selv;
    selv = (q==2) ? ov[2] : selv;
    selv = (q==3) ? ov[3] : selv;
    s_tile[(w*8+i)*66 + l] = selv;             // col o == l
  }
  __syncthreads();

  // coalesced transposed store: out[b][o][m0+pt]
  int o0 = tid >> 5, pt = tid & 31;
  int m0 = pbase & (M_-1);
  long outb = ((long)b*64) * M_ + m0 + pt;
  #pragma unroll
  for (int ii=0; ii<8; ii++){
    int o = o0*8 + ii;
    out[outb + (long)o*M_] = s_tile[pt*66 + o];
  }
}

extern "C" void kernel_launch(void* const* d_in, const int* in_sizes, int n_in,
                              void* d_out, int out_size, void* d_ws, size_t ws_size,
                              hipStream_t stream) {
  const float* center_pos = (const float*)d_in[0];
  const float* center_fea = (const float*)d_in[1];
  const float* pos        = (const float*)d_in[2];
  const float* fea        = (const float*)d_in[3];
  const int*   idx        = (const int*)d_in[4];
  const float* Wq = (const float*)d_in[5];   const float* bq = (const float*)d_in[6];
  const float* Wk = (const float*)d_in[7];   const float* bk = (const float*)d_in[8];
  const float* Wv = (const float*)d_in[9];   const float* bv = (const float*)d_in[10];
  const float* cpe_w1 = (const float*)d_in[11]; const float* cpe_s = (const float*)d_in[12];
  const float* cpe_b  = (const float*)d_in[13]; const float* cpe_w2 = (const float*)d_in[14];
  const float* cpe_b2 = (const float*)d_in[15];
  const float* pe_w1 = (const float*)d_in[16]; const float* pe_s = (const float*)d_in[17];
  const float* pe_b  = (const float*)d_in[18]; const float* pe_w2 = (const float*)d_in[19];
  const float* pe_b2 = (const float*)d_in[20];
  const float* we_w1 = (const float*)d_in[21]; const float* we_s = (const float*)d_in[22];
  const float* we_b  = (const float*)d_in[23]; const float* we_w2 = (const float*)d_in[24];
  const float* we_b2 = (const float*)d_in[25];

  // workspace (all bf16): xk 8.4MB | xv 8.4MB | qc 8.4MB  (25.2MB total)
  const size_t SZ = (size_t)B_*N_*64;
  u16* xk = (u16*)d_ws;
  u16* xv = xk + SZ;
  u16* qc = xv + SZ;
  float* outp = (float*)d_out;

  hipLaunchKernelGGL(pre_kernel, dim3(512), dim3(256), 0, stream,
      center_pos, center_fea, fea, Wq, bq, Wk, bk, Wv, bv,
      cpe_w1, cpe_s, cpe_b, cpe_w2, cpe_b2, xk, xv, qc);
  hipLaunchKernelGGL(attn_kernel, dim3(2048), dim3(256), 0, stream,
      center_pos, pos, idx, pe_w1, pe_s, pe_b, pe_w2, pe_b2,
      we_w1, we_s, we_b, we_w2, we_b2, xk, xv, qc, outp);
}

// Round 3
// 225.798 us; speedup vs baseline: 1.2645x; 1.2645x over previous
//
#include <hip/hip_runtime.h>
#include <hip/hip_bf16.h>

typedef unsigned short u16;
typedef __attribute__((ext_vector_type(8))) __bf16 bf8v;
typedef __attribute__((ext_vector_type(4))) float f32x4;
typedef __attribute__((ext_vector_type(4))) unsigned uint4v;

#define B_ 4
#define N_ 16384
#define M_ 16384
#define K_ 16
#define C_ 64
#define O_ 64
#define G_ 8

__device__ __forceinline__ float bf2f(u16 x){
  union { unsigned u; float f; } v; v.u = ((unsigned)x) << 16; return v.f;
}
__device__ __forceinline__ u16 f2bf(float f){
  union { float f; unsigned u; } v; v.f = f;
  unsigned u = v.u;
  return (u16)((u + 0x7FFFu + ((u >> 16) & 1u)) >> 16);
}

// ---------------------------------------------------------------------------
// Kernel 1: precompute via MFMA.
//   blocks [0,1024):    xk[b,n,:64]|xv[b,n,:64] = fea^T @ [Wk|Wv] + [bk|bv]  (bf16)
//   blocks [1024,2048): qw[m,g] = qc[m,:]@we_w1[:,g],
//                       qc = relu(cp@(cpe_w1*s)+cpe_b)@cpe_w2 - cf^T@Wq + (cpe_b2-bq)
//                       folded: qw = [H|cf] @ Bw + constw,  Bw=[cpe_w2;-Wq]@we_w1
// 64 points/block (4 waves x 16), K=64 (KV) / 128 (QC).
// MFMA 16x16x32 bf16: A[m=l&15][k=(l>>4)*8+j], B[k=(l>>4)*8+j][n=l&15],
//                     C/D: row=(l>>4)*4+reg, col=l&15.
// ---------------------------------------------------------------------------
__global__ __launch_bounds__(256) void pre_kernel(
    const float* __restrict__ center_pos, const float* __restrict__ center_fea,
    const float* __restrict__ fea,
    const float* __restrict__ Wq, const float* __restrict__ bq,
    const float* __restrict__ Wk, const float* __restrict__ bk,
    const float* __restrict__ Wv, const float* __restrict__ bv,
    const float* __restrict__ cpe_w1, const float* __restrict__ cpe_s, const float* __restrict__ cpe_b,
    const float* __restrict__ cpe_w2, const float* __restrict__ cpe_b2,
    const float* __restrict__ we_w1,
    u16* __restrict__ xk, u16* __restrict__ xv, float* __restrict__ qw)
{
  int tid = threadIdx.x;
  int blk = blockIdx.x;
  __shared__ u16 sWT[128*72];     // KV: WT[col][k] stride 72 ; QC: BwT[g][k] stride 136
  __shared__ u16 sOut[64*136];    // KV epilogue tile [pt][col 0..127], stride 136
  __shared__ float sMisc[784];

  int l = tid & 63, w = tid >> 6, c = l & 15, q = l >> 4;

  if (blk < 1024) {
    // ================= KV =================
    int P0 = blk * 64; int b = P0 >> 14; int n0 = P0 & (N_-1);
    for (int e = tid; e < 8192; e += 256){
      int k = e >> 7, col = e & 127;
      float v = (col < 64) ? Wk[k*64 + col] : Wv[k*64 + (col-64)];
      sWT[col*72 + k] = f2bf(v);
    }
    if (tid < 128) sMisc[tid] = (tid < 64) ? bk[tid] : bv[tid-64];
    __syncthreads();

    int mIdx = n0 + w*16 + c;               // n index for this lane's A-row
    const float* fb = fea + (long)b*C_*N_;
    bf8v af[2];
    #pragma unroll
    for (int ks=0; ks<2; ks++){
      union { bf8v v; u16 s[8]; } ua;
      #pragma unroll
      for (int j=0; j<8; j++)
        ua.s[j] = f2bf(fb[(long)(ks*32 + q*8 + j)*N_ + mIdx]);
      af[ks] = ua.v;
    }

    f32x4 acc[8];
    #pragma unroll
    for (int t=0; t<8; t++){
      float bias = sMisc[16*t + c];
      f32x4 a_ = {bias, bias, bias, bias};
      bf8v b0 = *(const bf8v*)&sWT[(16*t + c)*72 + q*8];
      bf8v b1 = *(const bf8v*)&sWT[(16*t + c)*72 + 32 + q*8];
      a_ = __builtin_amdgcn_mfma_f32_16x16x32_bf16(af[0], b0, a_, 0,0,0);
      a_ = __builtin_amdgcn_mfma_f32_16x16x32_bf16(af[1], b1, a_, 0,0,0);
      acc[t] = a_;
    }

    #pragma unroll
    for (int t=0; t<8; t++)
      #pragma unroll
      for (int r=0; r<4; r++)
        sOut[(w*16 + q*4 + r)*136 + 16*t + c] = f2bf(acc[t][r]);
    __syncthreads();

    #pragma unroll
    for (int rep=0; rep<4; rep++){
      int chunk = rep*256 + tid;            // 0..1023
      int pt = chunk >> 4, c8i = chunk & 15;
      uint4v val = *(const uint4v*)&sOut[pt*136 + c8i*8];
      int col8 = c8i*8;
      long row = (long)P0 + pt;
      if (col8 < 64) *(uint4v*)(xk + row*64 + col8)      = val;
      else           *(uint4v*)(xv + row*64 + (col8-64)) = val;
    }
  } else {
    // ================= QC -> qw =================
    int P0 = (blk - 1024) * 64; int b = P0 >> 14; int m0 = P0 & (M_-1);
    for (int e = tid; e < 512; e += 256) sMisc[e] = we_w1[e];       // [o*8+g]
    if (tid < 64){
      float sc = cpe_s[tid];
      sMisc[512+tid] = cpe_w1[tid]      * sc;
      sMisc[576+tid] = cpe_w1[64+tid]   * sc;
      sMisc[640+tid] = cpe_w1[128+tid]  * sc;
      sMisc[704+tid] = cpe_b[tid];
    }
    __syncthreads();

    // Bw[k][g] = sum_o B2[k][o]*we1[o][g],  B2 = [cpe_w2 ; -Wq]  -> BwT[g][k]
    {
      int k = tid >> 1, g0 = (tid & 1)*4;
      const float* brow = (k < 64) ? (cpe_w2 + k*64) : (Wq + (k-64)*64);
      float sgn = (k < 64) ? 1.f : -1.f;
      float aw[4] = {0.f,0.f,0.f,0.f};
      for (int o=0; o<64; o++){
        float bo = brow[o]*sgn;
        #pragma unroll
        for (int gg=0; gg<4; gg++) aw[gg] += bo * sMisc[o*8 + g0+gg];
      }
      #pragma unroll
      for (int gg=0; gg<4; gg++) sWT[(g0+gg)*136 + k] = f2bf(aw[gg]);
    }
    for (int e = tid; e < 1088; e += 256) sWT[1088 + e] = 0;        // zero rows g=8..15
    if (tid < 8){
      float s = 0.f;
      for (int o=0; o<64; o++) s += (cpe_b2[o] - bq[o]) * sMisc[o*8 + tid];
      sMisc[768 + tid] = s;
    }
    __syncthreads();

    int pg = P0 + w*16 + c;                  // global point
    int mIdx = m0 + w*16 + c;
    long c3 = (long)pg * 3;
    float cp0 = center_pos[c3], cp1 = center_pos[c3+1], cp2 = center_pos[c3+2];
    bf8v ah[2], acf[2];
    #pragma unroll
    for (int ks=0; ks<2; ks++){
      union { bf8v v; u16 s[8]; } ua;
      #pragma unroll
      for (int j=0; j<8; j++){
        int h = ks*32 + q*8 + j;
        float hv = cp0*sMisc[512+h] + cp1*sMisc[576+h] + cp2*sMisc[640+h] + sMisc[704+h];
        ua.s[j] = f2bf(fmaxf(hv, 0.f));
      }
      ah[ks] = ua.v;
    }
    const float* cfb = center_fea + (long)b*C_*M_;
    #pragma unroll
    for (int ks=0; ks<2; ks++){
      union { bf8v v; u16 s[8]; } ua;
      #pragma unroll
      for (int j=0; j<8; j++)
        ua.s[j] = f2bf(cfb[(long)(ks*32 + q*8 + j)*M_ + mIdx]);
      acf[ks] = ua.v;
    }

    float cinit = (c < 8) ? sMisc[768 + c] : 0.f;
    f32x4 aq = {cinit, cinit, cinit, cinit};
    {
      bf8v b0 = *(const bf8v*)&sWT[c*136 + q*8];
      bf8v b1 = *(const bf8v*)&sWT[c*136 + 32 + q*8];
      bf8v b2 = *(const bf8v*)&sWT[c*136 + 64 + q*8];
      bf8v b3 = *(const bf8v*)&sWT[c*136 + 96 + q*8];
      aq = __builtin_amdgcn_mfma_f32_16x16x32_bf16(ah[0], b0, aq, 0,0,0);
      aq = __builtin_amdgcn_mfma_f32_16x16x32_bf16(ah[1], b1, aq, 0,0,0);
      aq = __builtin_amdgcn_mfma_f32_16x16x32_bf16(acf[0], b2, aq, 0,0,0);
      aq = __builtin_amdgcn_mfma_f32_16x16x32_bf16(acf[1], b3, aq, 0,0,0);
    }
    __syncthreads();                          // done reading sMisc weights
    if (c < 8){
      #pragma unroll
      for (int r=0; r<4; r++) sMisc[(w*16 + q*4 + r)*8 + c] = aq[r];
    }
    __syncthreads();
    for (int e = tid; e < 512; e += 256)
      qw[(long)P0*8 + e] = sMisc[e];
  }
}

// ---------------------------------------------------------------------------
// Kernel 2: main attention. 1 wave = 1 m-point (8 points/wave, 32/block).
// ---------------------------------------------------------------------------
__global__ __launch_bounds__(256) void attn_kernel(
    const float* __restrict__ center_pos, const float* __restrict__ pos,
    const int* __restrict__ idx,
    const float* __restrict__ pe_w1, const float* __restrict__ pe_s, const float* __restrict__ pe_b,
    const float* __restrict__ pe_w2, const float* __restrict__ pe_b2,
    const float* __restrict__ we_w1, const float* __restrict__ we_s, const float* __restrict__ we_b,
    const float* __restrict__ we_w2, const float* __restrict__ we_b2,
    const u16* __restrict__ xk, const u16* __restrict__ xv, const float* __restrict__ qw,
    float* __restrict__ out)
{
  int tid = threadIdx.x;
  __shared__ float s_w1f[192];     // pe_w1 * pe_s folded
  __shared__ float s_pb[64];       // pe_b
  __shared__ float s_ws[8], s_wb[8], s_wb2[8];
  __shared__ float s_ww2[64];      // we_w2 [8][8]
  __shared__ float s_pb2[64];      // pe_b2
  __shared__ u16  s_vt[4*16*72];   // per-wave gathered V tile [k][o], stride 72
  __shared__ float s_tile[32*66];  // out tile [pt][o], padded

  if (tid < 64){
    float sc = pe_s[tid];
    s_w1f[tid]     = pe_w1[tid]*sc;
    s_w1f[64+tid]  = pe_w1[64+tid]*sc;
    s_w1f[128+tid] = pe_w1[128+tid]*sc;
    s_pb[tid]  = pe_b[tid];
    s_pb2[tid] = pe_b2[tid];
    s_ww2[tid] = we_w2[tid];
  }
  if (tid >= 64 && tid < 72){
    int g = tid-64;
    s_ws[g]=we_s[g]; s_wb[g]=we_b[g]; s_wb2[g]=we_b2[g];
  }
  __syncthreads();

  int w = tid >> 6, l = tid & 63, c = l & 15, q = l >> 4, c8 = c & 7, qb = l & 48;

  // static B-fragments (registers)
  bf8v pw2f[4][2], ww1f[2];
  {
    union { bf8v v; u16 s[8]; } u_;
    #pragma unroll
    for (int t=0;t<4;t++)
      #pragma unroll
      for (int ks=0;ks<2;ks++){
        #pragma unroll
        for (int j=0;j<8;j++) u_.s[j] = f2bf(pe_w2[(ks*32 + q*8 + j)*64 + t*16 + c]);
        pw2f[t][ks] = u_.v;
      }
    #pragma unroll
    for (int ks=0;ks<2;ks++){
      #pragma unroll
      for (int j=0;j<8;j++) u_.s[j] = (c < 8) ? f2bf(we_w1[(ks*32 + q*8 + j)*8 + c]) : (u16)0;
      ww1f[ks] = u_.v;
    }
  }
  float ws_c = s_ws[c8], wb_c = s_wb[c8], wb2_c = s_wb2[c8];
  float w2col[8];
  #pragma unroll
  for (int g=0; g<8; g++) w2col[g] = s_ww2[g*8 + c8];
  float pb2t[4];
  #pragma unroll
  for (int t=0;t<4;t++) pb2t[t] = s_pb2[t*16 + c];

  int pbase = blockIdx.x * 32;
  int b = pbase >> 14;
  long xkb = (long)b * N_ * 64;
  u16* vt = s_vt + w*(16*72);

  // software-pipelined scalars for i=0
  int p = pbase + w*8;
  int iv = idx[(long)p*16 + c];
  float qpv = qw[(long)p*8 + c8];
  long c30 = (long)p*3;
  float cp0 = center_pos[c30], cp1 = center_pos[c30+1], cp2 = center_pos[c30+2];

  #pragma unroll 1
  for (int i = 0; i < 8; i++){
    // current i's gathers (addresses ready thanks to prefetch)
    long pr3 = ((long)b*N_ + iv) * 3;
    float np0 = pos[pr3]   - cp0;
    float np1 = pos[pr3+1] - cp1;
    float np2 = pos[pr3+2] - cp2;
    const u16* krow = xk + xkb + (long)iv * 64;
    bf8v ka0 = *(const bf8v*)(krow + q*8);
    bf8v ka1 = *(const bf8v*)(krow + 32 + q*8);
    const u16* vrow = xv + xkb + (long)iv * 64;
    uint4v va0 = *(const uint4v*)(vrow + q*8);
    uint4v va1 = *(const uint4v*)(vrow + 32 + q*8);

    // prefetch scalars for i+1
    int pn = p + ((i < 7) ? 1 : 0);
    int iv_n = idx[(long)pn*16 + c];
    float qpv_n = qw[(long)pn*8 + c8];
    long c3n = (long)pn*3;
    float cpn0 = center_pos[c3n], cpn1 = center_pos[c3n+1], cpn2 = center_pos[c3n+2];

    // stash gathered V rows in A-layout (intra-wave LDS, no barrier needed)
    *(uint4v*)&vt[c*72 + q*8]      = va0;
    *(uint4v*)&vt[c*72 + 32 + q*8] = va1;

    // H1 = relu(npos @ pe_w1 * s + b), built directly as A-fragments
    bf8v h1f[2];
    {
      union { bf8v v; u16 s[8]; } hu;
      #pragma unroll
      for (int ks=0;ks<2;ks++){
        #pragma unroll
        for (int j=0;j<8;j++){
          int o = ks*32 + q*8 + j;
          float hv = np0*s_w1f[o] + np1*s_w1f[64+o] + np2*s_w1f[128+o] + s_pb[o];
          hu.s[j] = f2bf(fmaxf(hv, 0.f));
        }
        h1f[ks] = hu.v;
      }
    }

    f32x4 h2a = {qpv, qpv, qpv, qpv};
    h2a = __builtin_amdgcn_mfma_f32_16x16x32_bf16(ka0, ww1f[0], h2a, 0, 0, 0);
    h2a = __builtin_amdgcn_mfma_f32_16x16x32_bf16(ka1, ww1f[1], h2a, 0, 0, 0);

    f32x4 prA[4];
    #pragma unroll
    for (int t=0;t<4;t++){
      f32x4 z = {0.f,0.f,0.f,0.f};
      z = __builtin_amdgcn_mfma_f32_16x16x32_bf16(h1f[0], pw2f[t][0], z, 0, 0, 0);
      z = __builtin_amdgcn_mfma_f32_16x16x32_bf16(h1f[1], pw2f[t][1], z, 0, 0, 0);
      prA[t] = z;
    }

    // weight-encode MLP tail + softmax over the 16 neighbors
    float h2r[4];
    #pragma unroll
    for (int r=0;r<4;r++) h2r[r] = fmaxf(h2a[r]*ws_c + wb_c, 0.f);
    float wl[4] = {wb2_c, wb2_c, wb2_c, wb2_c};
    #pragma unroll
    for (int g=0; g<8; g++){
      float wg = w2col[g];
      #pragma unroll
      for (int r=0;r<4;r++)
        wl[r] += __shfl(h2r[r], qb | g, 64) * wg;
    }
    float mx = fmaxf(fmaxf(wl[0],wl[1]), fmaxf(wl[2],wl[3]));
    mx = fmaxf(mx, __shfl_xor(mx, 16, 64));
    mx = fmaxf(mx, __shfl_xor(mx, 32, 64));
    float e[4];
    #pragma unroll
    for (int r=0;r<4;r++) e[r] = exp2f((wl[r]-mx)*1.44269504f);
    float sm = e[0]+e[1]+e[2]+e[3];
    sm += __shfl_xor(sm, 16, 64);
    sm += __shfl_xor(sm, 32, 64);
    float rn = 1.0f / sm;
    #pragma unroll
    for (int r=0;r<4;r++) e[r] *= rn;          // e[r] = W[k=q*4+r][g=c]

    // out[o] = sum_k (nv + pr)[k][o] * W[k][o>>3]   (pe_b2 folded via sum(W)=1)
    float ov[4] = {0.f,0.f,0.f,0.f};
    int ch = c >> 3;
    #pragma unroll
    for (int r=0;r<4;r++){
      #pragma unroll
      for (int t=0;t<4;t++){
        float wv_ = __shfl(e[r], qb | (t*2 + ch), 64);
        float nvv = bf2f(vt[(q*4+r)*72 + t*16 + c]);
        ov[t] += (prA[t][r] + nvv) * wv_;
      }
    }
    #pragma unroll
    for (int t=0;t<4;t++){
      ov[t] += __shfl_xor(ov[t], 16, 64);
      ov[t] += __shfl_xor(ov[t], 32, 64);
      ov[t] += pb2t[t];
    }
    float selv = ov[0];
    selv = (q==1) ? ov[1] : selv;
    selv = (q==2) ? ov[2] : selv;
    selv = (q==3) ? ov[3] : selv;
    s_tile[(w*8+i)*66 + l] = selv;             // col o == l

    p = pn; iv = iv_n; qpv = qpv_n; cp0 = cpn0; cp1 = cpn1; cp2 = cpn2;
  }
  __syncthreads();

  // coalesced transposed store: out[b][o][m0+pt]
  int o0 = tid >> 5, pt = tid & 31;
  int m0 = pbase & (M_-1);
  long outb = ((long)b*64) * M_ + m0 + pt;
  #pragma unroll
  for (int ii=0; ii<8; ii++){
    int o = o0*8 + ii;
    out[outb + (long)o*M_] = s_tile[pt*66 + o];
  }
}

extern "C" void kernel_launch(void* const* d_in, const int* in_sizes, int n_in,
                              void* d_out, int out_size, void* d_ws, size_t ws_size,
                              hipStream_t stream) {
  const float* center_pos = (const float*)d_in[0];
  const float* center_fea = (const float*)d_in[1];
  const float* pos        = (const float*)d_in[2];
  const float* fea        = (const float*)d_in[3];
  const int*   idx        = (const int*)d_in[4];
  const float* Wq = (const float*)d_in[5];   const float* bq = (const float*)d_in[6];
  const float* Wk = (const float*)d_in[7];   const float* bk = (const float*)d_in[8];
  const float* Wv = (const float*)d_in[9];   const float* bv = (const float*)d_in[10];
  const float* cpe_w1 = (const float*)d_in[11]; const float* cpe_s = (const float*)d_in[12];
  const float* cpe_b  = (const float*)d_in[13]; const float* cpe_w2 = (const float*)d_in[14];
  const float* cpe_b2 = (const float*)d_in[15];
  const float* pe_w1 = (const float*)d_in[16]; const float* pe_s = (const float*)d_in[17];
  const float* pe_b  = (const float*)d_in[18]; const float* pe_w2 = (const float*)d_in[19];
  const float* pe_b2 = (const float*)d_in[20];
  const float* we_w1 = (const float*)d_in[21]; const float* we_s = (const float*)d_in[22];
  const float* we_b  = (const float*)d_in[23]; const float* we_w2 = (const float*)d_in[24];
  const float* we_b2 = (const float*)d_in[25];

  // workspace: xk bf16 8.4MB | xv bf16 8.4MB | qw f32 2.1MB
  const size_t SZ = (size_t)B_*N_*64;
  u16* xk = (u16*)d_ws;
  u16* xv = xk + SZ;
  float* qwp = (float*)(xv + SZ);
  float* outp = (float*)d_out;

  hipLaunchKernelGGL(pre_kernel, dim3(2048), dim3(256), 0, stream,
      center_pos, center_fea, fea, Wq, bq, Wk, bk, Wv, bv,
      cpe_w1, cpe_s, cpe_b, cpe_w2, cpe_b2, we_w1, xk, xv, qwp);
  hipLaunchKernelGGL(attn_kernel, dim3(2048), dim3(256), 0, stream,
      center_pos, pos, idx, pe_w1, pe_s, pe_b, pe_w2, pe_b2,
      we_w1, we_s, we_b, we_w2, we_b2, xk, xv, qwp, outp);
}

// Round 4
// 213.079 us; speedup vs baseline: 1.3400x; 1.0597x over previous
//
#include <hip/hip_runtime.h>
#include <hip/hip_bf16.h>

typedef unsigned short u16;
typedef __attribute__((ext_vector_type(8))) __bf16 bf8v;
typedef __attribute__((ext_vector_type(4))) float f32x4;
typedef __attribute__((ext_vector_type(4))) unsigned uint4v;

#define B_ 4
#define N_ 16384
#define M_ 16384
#define K_ 16
#define C_ 64
#define O_ 64
#define G_ 8

__device__ __forceinline__ float bf2f(u16 x){
  union { unsigned u; float f; } v; v.u = ((unsigned)x) << 16; return v.f;
}
__device__ __forceinline__ u16 f2bf(float f){
  union { float f; unsigned u; } v; v.f = f;
  unsigned u = v.u;
  return (u16)((u + 0x7FFFu + ((u >> 16) & 1u)) >> 16);
}
union pk2 { unsigned u; _Float16 h[2]; };
__device__ __forceinline__ unsigned packh(float a, float b){
  pk2 p; p.h[0] = (_Float16)a; p.h[1] = (_Float16)b; return p.u;
}

// ---------------------------------------------------------------------------
// Kernel 1: precompute via MFMA. 256 points/block, 4 sub-iters of 64.
//   blocks [0,256):   xk|xv = fea^T @ [Wk|Wv] + [bk|bv]  (bf16)
//   blocks [256,512): qw[m,g] = ([H|cf] @ Bw + constw),  Bw=[cpe_w2;-Wq]@we_w1
// MFMA 16x16x32 bf16: A[m=l&15][k=(l>>4)*8+j], B[k=(l>>4)*8+j][n=l&15],
//                     C/D: row=(l>>4)*4+reg, col=l&15.
// ---------------------------------------------------------------------------
__global__ __launch_bounds__(256) void pre_kernel(
    const float* __restrict__ center_pos, const float* __restrict__ center_fea,
    const float* __restrict__ fea,
    const float* __restrict__ Wq, const float* __restrict__ bq,
    const float* __restrict__ Wk, const float* __restrict__ bk,
    const float* __restrict__ Wv, const float* __restrict__ bv,
    const float* __restrict__ cpe_w1, const float* __restrict__ cpe_s, const float* __restrict__ cpe_b,
    const float* __restrict__ cpe_w2, const float* __restrict__ cpe_b2,
    const float* __restrict__ we_w1,
    u16* __restrict__ xk, u16* __restrict__ xv, float* __restrict__ qw)
{
  int tid = threadIdx.x;
  int blk = blockIdx.x;
  __shared__ u16 sWT[128*72];     // KV: WT[col][k] stride 72 ; QC: BwT[g][k] stride 136
  __shared__ u16 sOut[64*136];    // KV epilogue tile [pt][col 0..127], stride 136
  __shared__ float sMisc[784];

  int l = tid & 63, w = tid >> 6, c = l & 15, q = l >> 4;

  if (blk < 256) {
    // ================= KV =================
    int P0 = blk * 256; int b = P0 >> 14; int n00 = P0 & (N_-1);
    const float* fb = fea + (long)b*C_*N_;

    // prefetch A-loads for sub-iter 0 (before staging, loads in flight)
    float ar[16];
    {
      int mI = n00 + w*16 + c;
      #pragma unroll
      for (int e=0; e<16; e++)
        ar[e] = fb[(long)((e>>3)*32 + q*8 + (e&7))*N_ + mI];
    }

    for (int e = tid; e < 8192; e += 256){
      int k = e >> 7, col = e & 127;
      float v = (col < 64) ? Wk[k*64 + col] : Wv[k*64 + (col-64)];
      sWT[col*72 + k] = f2bf(v);
    }
    if (tid < 128) sMisc[tid] = (tid < 64) ? bk[tid] : bv[tid-64];
    __syncthreads();

    #pragma unroll 1
    for (int s = 0; s < 4; s++){
      bf8v af[2];
      #pragma unroll
      for (int ks=0; ks<2; ks++){
        union { bf8v v; u16 sv[8]; } ua;
        #pragma unroll
        for (int j=0; j<8; j++) ua.sv[j] = f2bf(ar[ks*8+j]);
        af[ks] = ua.v;
      }
      // prefetch next sub-iter
      if (s < 3){
        int mI = n00 + (s+1)*64 + w*16 + c;
        #pragma unroll
        for (int e=0; e<16; e++)
          ar[e] = fb[(long)((e>>3)*32 + q*8 + (e&7))*N_ + mI];
      }

      f32x4 acc[8];
      #pragma unroll
      for (int t=0; t<8; t++){
        float bias = sMisc[16*t + c];
        f32x4 a_ = {bias, bias, bias, bias};
        bf8v b0 = *(const bf8v*)&sWT[(16*t + c)*72 + q*8];
        bf8v b1 = *(const bf8v*)&sWT[(16*t + c)*72 + 32 + q*8];
        a_ = __builtin_amdgcn_mfma_f32_16x16x32_bf16(af[0], b0, a_, 0,0,0);
        a_ = __builtin_amdgcn_mfma_f32_16x16x32_bf16(af[1], b1, a_, 0,0,0);
        acc[t] = a_;
      }

      #pragma unroll
      for (int t=0; t<8; t++)
        #pragma unroll
        for (int r=0; r<4; r++)
          sOut[(w*16 + q*4 + r)*136 + 16*t + c] = f2bf(acc[t][r]);
      __syncthreads();

      long Ps = P0 + s*64;
      #pragma unroll
      for (int rep=0; rep<4; rep++){
        int chunk = rep*256 + tid;            // 0..1023
        int pt = chunk >> 4, c8i = chunk & 15;
        uint4v val = *(const uint4v*)&sOut[pt*136 + c8i*8];
        int col8 = c8i*8;
        long row = Ps + pt;
        if (col8 < 64) *(uint4v*)(xk + row*64 + col8)      = val;
        else           *(uint4v*)(xv + row*64 + (col8-64)) = val;
      }
      __syncthreads();
    }
  } else {
    // ================= QC -> qw =================
    int P0 = (blk - 256) * 256; int b = P0 >> 14; int m00 = P0 & (M_-1);
    const float* cfb = center_fea + (long)b*C_*M_;

    // prefetch cf/cp for sub-iter 0
    float cfr[16], cpr[3];
    {
      int mI = m00 + w*16 + c;
      #pragma unroll
      for (int e=0; e<16; e++)
        cfr[e] = cfb[(long)((e>>3)*32 + q*8 + (e&7))*M_ + mI];
      long c3 = (long)(P0 + w*16 + c)*3;
      cpr[0]=center_pos[c3]; cpr[1]=center_pos[c3+1]; cpr[2]=center_pos[c3+2];
    }

    for (int e = tid; e < 512; e += 256) sMisc[e] = we_w1[e];       // [o*8+g]
    if (tid < 64){
      float sc = cpe_s[tid];
      sMisc[512+tid] = cpe_w1[tid]      * sc;
      sMisc[576+tid] = cpe_w1[64+tid]   * sc;
      sMisc[640+tid] = cpe_w1[128+tid]  * sc;
      sMisc[704+tid] = cpe_b[tid];
    }
    __syncthreads();

    // Bw[k][g] = sum_o B2[k][o]*we1[o][g],  B2 = [cpe_w2 ; -Wq]  -> BwT[g][k]
    {
      int k = tid >> 1, g0 = (tid & 1)*4;
      const float* brow = (k < 64) ? (cpe_w2 + k*64) : (Wq + (k-64)*64);
      float sgn = (k < 64) ? 1.f : -1.f;
      float aw[4] = {0.f,0.f,0.f,0.f};
      for (int o=0; o<64; o++){
        float bo = brow[o]*sgn;
        #pragma unroll
        for (int gg=0; gg<4; gg++) aw[gg] += bo * sMisc[o*8 + g0+gg];
      }
      #pragma unroll
      for (int gg=0; gg<4; gg++) sWT[(g0+gg)*136 + k] = f2bf(aw[gg]);
    }
    for (int e = tid; e < 1088; e += 256) sWT[1088 + e] = 0;        // zero rows g=8..15
    if (tid < 8){
      float s = 0.f;
      for (int o=0; o<64; o++) s += (cpe_b2[o] - bq[o]) * sMisc[o*8 + tid];
      sMisc[768 + tid] = s;
    }
    __syncthreads();

    #pragma unroll 1
    for (int s = 0; s < 4; s++){
      // build A-frags from prefetched raw data
      bf8v ah[2], acf[2];
      #pragma unroll
      for (int ks=0; ks<2; ks++){
        union { bf8v v; u16 sv[8]; } ua;
        #pragma unroll
        for (int j=0; j<8; j++){
          int h = ks*32 + q*8 + j;
          float hv = cpr[0]*sMisc[512+h] + cpr[1]*sMisc[576+h] + cpr[2]*sMisc[640+h] + sMisc[704+h];
          ua.sv[j] = f2bf(fmaxf(hv, 0.f));
        }
        ah[ks] = ua.v;
      }
      #pragma unroll
      for (int ks=0; ks<2; ks++){
        union { bf8v v; u16 sv[8]; } ua;
        #pragma unroll
        for (int j=0; j<8; j++) ua.sv[j] = f2bf(cfr[ks*8+j]);
        acf[ks] = ua.v;
      }
      // prefetch next
      if (s < 3){
        int mI = m00 + (s+1)*64 + w*16 + c;
        #pragma unroll
        for (int e=0; e<16; e++)
          cfr[e] = cfb[(long)((e>>3)*32 + q*8 + (e&7))*M_ + mI];
        long c3 = (long)(P0 + (s+1)*64 + w*16 + c)*3;
        cpr[0]=center_pos[c3]; cpr[1]=center_pos[c3+1]; cpr[2]=center_pos[c3+2];
      }

      float cinit = (c < 8) ? sMisc[768 + c] : 0.f;
      f32x4 aq = {cinit, cinit, cinit, cinit};
      {
        bf8v b0 = *(const bf8v*)&sWT[c*136 + q*8];
        bf8v b1 = *(const bf8v*)&sWT[c*136 + 32 + q*8];
        bf8v b2 = *(const bf8v*)&sWT[c*136 + 64 + q*8];
        bf8v b3 = *(const bf8v*)&sWT[c*136 + 96 + q*8];
        aq = __builtin_amdgcn_mfma_f32_16x16x32_bf16(ah[0], b0, aq, 0,0,0);
        aq = __builtin_amdgcn_mfma_f32_16x16x32_bf16(ah[1], b1, aq, 0,0,0);
        aq = __builtin_amdgcn_mfma_f32_16x16x32_bf16(acf[0], b2, aq, 0,0,0);
        aq = __builtin_amdgcn_mfma_f32_16x16x32_bf16(acf[1], b3, aq, 0,0,0);
      }
      if (c < 8){
        #pragma unroll
        for (int r=0; r<4; r++) sOut[(w*16 + q*4 + r)*8 + c] = 0; // touch to keep layout simple
      }
      __syncthreads();
      if (c < 8){
        #pragma unroll
        for (int r=0; r<4; r++) ((float*)sOut)[(w*16 + q*4 + r)*8 + c] = aq[r];
      }
      __syncthreads();
      for (int e = tid; e < 512; e += 256)
        qw[(long)(P0 + s*64)*8 + e] = ((float*)sOut)[e];
      __syncthreads();
    }
  }
}

// ---------------------------------------------------------------------------
// Kernel 2: main attention. 1 wave = 1 m-point (8 points/wave, 32/block).
// Full one-iteration-ahead prefetch of gathers; f16-packed shuffle broadcasts.
// ---------------------------------------------------------------------------
__global__ __launch_bounds__(256) void attn_kernel(
    const float* __restrict__ center_pos, const float* __restrict__ pos,
    const int* __restrict__ idx,
    const float* __restrict__ pe_w1, const float* __restrict__ pe_s, const float* __restrict__ pe_b,
    const float* __restrict__ pe_w2, const float* __restrict__ pe_b2,
    const float* __restrict__ we_w1, const float* __restrict__ we_s, const float* __restrict__ we_b,
    const float* __restrict__ we_w2, const float* __restrict__ we_b2,
    const u16* __restrict__ xk, const u16* __restrict__ xv, const float* __restrict__ qw,
    float* __restrict__ out)
{
  int tid = threadIdx.x;
  __shared__ float s_w1f[192];     // pe_w1 * pe_s folded
  __shared__ float s_pb[64];       // pe_b
  __shared__ float s_ws[8], s_wb[8];
  __shared__ float s_ww2[64];      // we_w2 [8][8]
  __shared__ float s_pb2[64];      // pe_b2
  __shared__ float s_wb2[8];
  __shared__ u16  s_vt[4*16*72];   // per-wave gathered V tile [k][o], stride 72
  __shared__ float s_tile[32*66];  // out tile [pt][o], padded

  if (tid < 64){
    float sc = pe_s[tid];
    s_w1f[tid]     = pe_w1[tid]*sc;
    s_w1f[64+tid]  = pe_w1[64+tid]*sc;
    s_w1f[128+tid] = pe_w1[128+tid]*sc;
    s_pb[tid]  = pe_b[tid];
    s_pb2[tid] = pe_b2[tid];
    s_ww2[tid] = we_w2[tid];
  }
  if (tid >= 64 && tid < 72){
    int g = tid-64;
    s_ws[g]=we_s[g]; s_wb[g]=we_b[g]; s_wb2[g]=we_b2[g];
  }
  __syncthreads();

  int w = tid >> 6, l = tid & 63, c = l & 15, q = l >> 4, c8 = c & 7, qb = l & 48;

  // static B-fragments (registers)
  bf8v pw2f[4][2], ww1f[2];
  {
    union { bf8v v; u16 s[8]; } u_;
    #pragma unroll
    for (int t=0;t<4;t++)
      #pragma unroll
      for (int ks=0;ks<2;ks++){
        #pragma unroll
        for (int j=0;j<8;j++) u_.s[j] = f2bf(pe_w2[(ks*32 + q*8 + j)*64 + t*16 + c]);
        pw2f[t][ks] = u_.v;
      }
    #pragma unroll
    for (int ks=0;ks<2;ks++){
      #pragma unroll
      for (int j=0;j<8;j++) u_.s[j] = (c < 8) ? f2bf(we_w1[(ks*32 + q*8 + j)*8 + c]) : (u16)0;
      ww1f[ks] = u_.v;
    }
  }
  float ws_c = s_ws[c8], wb_c = s_wb[c8], wb2_c = s_wb2[c8];
  float w2col[8];
  #pragma unroll
  for (int g=0; g<8; g++) w2col[g] = s_ww2[g*8 + c8];
  float pb2t[4];
  #pragma unroll
  for (int t=0;t<4;t++) pb2t[t] = s_pb2[t*16 + c];

  int pbase = blockIdx.x * 32;
  int b = pbase >> 14;
  long xkb = (long)b * N_ * 64;
  u16* vt = s_vt + w*(16*72);

  // --- prefetch everything for i=0 ---
  int p = pbase + w*8;
  int iv = idx[(long)p*16 + c];
  float qpv = qw[(long)p*8 + c8];
  long c30 = (long)p*3;
  float cp0 = center_pos[c30], cp1 = center_pos[c30+1], cp2 = center_pos[c30+2];
  long pr30 = ((long)b*N_ + iv) * 3;
  float px = pos[pr30], py = pos[pr30+1], pz = pos[pr30+2];
  const u16* krow0 = xk + xkb + (long)iv * 64;
  bf8v ka0 = *(const bf8v*)(krow0 + q*8);
  bf8v ka1 = *(const bf8v*)(krow0 + 32 + q*8);
  const u16* vrow0 = xv + xkb + (long)iv * 64;
  uint4v va0 = *(const uint4v*)(vrow0 + q*8);
  uint4v va1 = *(const uint4v*)(vrow0 + 32 + q*8);

  #pragma unroll 1
  for (int i = 0; i < 8; i++){
    // ---- prefetch i+1 (scalars then dependent gathers) ----
    int pn = p + ((i < 7) ? 1 : 0);
    int iv_n = idx[(long)pn*16 + c];
    float qpv_n = qw[(long)pn*8 + c8];
    long c3n = (long)pn*3;
    float cpn0 = center_pos[c3n], cpn1 = center_pos[c3n+1], cpn2 = center_pos[c3n+2];
    long pr3n = ((long)b*N_ + iv_n) * 3;
    float pxn = pos[pr3n], pyn = pos[pr3n+1], pzn = pos[pr3n+2];
    const u16* krn = xk + xkb + (long)iv_n * 64;
    bf8v kan0 = *(const bf8v*)(krn + q*8);
    bf8v kan1 = *(const bf8v*)(krn + 32 + q*8);
    const u16* vrn = xv + xkb + (long)iv_n * 64;
    uint4v van0 = *(const uint4v*)(vrn + q*8);
    uint4v van1 = *(const uint4v*)(vrn + 32 + q*8);

    // ---- current point ----
    float np0 = px - cp0, np1 = py - cp1, np2 = pz - cp2;

    // stash gathered V rows in A-layout (intra-wave LDS, no barrier needed)
    *(uint4v*)&vt[c*72 + q*8]      = va0;
    *(uint4v*)&vt[c*72 + 32 + q*8] = va1;

    // H1 = relu(npos @ pe_w1 * s + b), built directly as A-fragments
    bf8v h1f[2];
    {
      union { bf8v v; u16 s[8]; } hu;
      #pragma unroll
      for (int ks=0;ks<2;ks++){
        #pragma unroll
        for (int j=0;j<8;j++){
          int o = ks*32 + q*8 + j;
          float hv = np0*s_w1f[o] + np1*s_w1f[64+o] + np2*s_w1f[128+o] + s_pb[o];
          hu.s[j] = f2bf(fmaxf(hv, 0.f));
        }
        h1f[ks] = hu.v;
      }
    }

    f32x4 h2a = {qpv, qpv, qpv, qpv};
    h2a = __builtin_amdgcn_mfma_f32_16x16x32_bf16(ka0, ww1f[0], h2a, 0, 0, 0);
    h2a = __builtin_amdgcn_mfma_f32_16x16x32_bf16(ka1, ww1f[1], h2a, 0, 0, 0);

    f32x4 prA[4];
    #pragma unroll
    for (int t=0;t<4;t++){
      f32x4 z = {0.f,0.f,0.f,0.f};
      z = __builtin_amdgcn_mfma_f32_16x16x32_bf16(h1f[0], pw2f[t][0], z, 0, 0, 0);
      z = __builtin_amdgcn_mfma_f32_16x16x32_bf16(h1f[1], pw2f[t][1], z, 0, 0, 0);
      prA[t] = z;
    }

    // weight-encode MLP tail (f16-packed broadcasts) + softmax (no max-sub)
    float h2r[4];
    #pragma unroll
    for (int r=0;r<4;r++) h2r[r] = fmaxf(h2a[r]*ws_c + wb_c, 0.f);
    unsigned hp0 = packh(h2r[0], h2r[1]);
    unsigned hp1 = packh(h2r[2], h2r[3]);
    float wl[4] = {wb2_c, wb2_c, wb2_c, wb2_c};
    #pragma unroll
    for (int g=0; g<8; g++){
      float wg = w2col[g];
      pk2 u0; u0.u = (unsigned)__shfl((int)hp0, qb | g, 64);
      pk2 u1; u1.u = (unsigned)__shfl((int)hp1, qb | g, 64);
      wl[0] += (float)u0.h[0] * wg;
      wl[1] += (float)u0.h[1] * wg;
      wl[2] += (float)u1.h[0] * wg;
      wl[3] += (float)u1.h[1] * wg;
    }
    float e[4];
    #pragma unroll
    for (int r=0;r<4;r++) e[r] = exp2f(wl[r]*1.44269504f);
    float sm = e[0]+e[1]+e[2]+e[3];
    sm += __shfl_xor(sm, 16, 64);
    sm += __shfl_xor(sm, 32, 64);
    float rn = 1.0f / sm;
    #pragma unroll
    for (int r=0;r<4;r++) e[r] *= rn;          // e[r] = W[k=q*4+r][g=c8]
    unsigned ep0 = packh(e[0], e[1]);
    unsigned ep1 = packh(e[2], e[3]);

    // out[o] = sum_k (nv + pr)[k][o] * W[k][o>>3]   (pe_b2 folded via sum(W)=1)
    float ov[4] = {0.f,0.f,0.f,0.f};
    int ch = c >> 3;
    #pragma unroll
    for (int t=0;t<4;t++){
      int src = qb | (t*2 + ch);
      pk2 w01; w01.u = (unsigned)__shfl((int)ep0, src, 64);
      pk2 w23; w23.u = (unsigned)__shfl((int)ep1, src, 64);
      float wv0 = (float)w01.h[0], wv1 = (float)w01.h[1];
      float wv2 = (float)w23.h[0], wv3 = (float)w23.h[1];
      float acc = 0.f;
      acc += (prA[t][0] + bf2f(vt[(q*4+0)*72 + t*16 + c])) * wv0;
      acc += (prA[t][1] + bf2f(vt[(q*4+1)*72 + t*16 + c])) * wv1;
      acc += (prA[t][2] + bf2f(vt[(q*4+2)*72 + t*16 + c])) * wv2;
      acc += (prA[t][3] + bf2f(vt[(q*4+3)*72 + t*16 + c])) * wv3;
      ov[t] = acc;
    }
    #pragma unroll
    for (int t=0;t<4;t++){
      ov[t] += __shfl_xor(ov[t], 16, 64);
      ov[t] += __shfl_xor(ov[t], 32, 64);
      ov[t] += pb2t[t];
    }
    float selv = ov[0];
    selv = (q==1) ? ov[1] : selv;
    selv = (q==2) ? ov[2] : selv;
    selv = (q==3) ? ov[3] : selv;
    s_tile[(w*8+i)*66 + l] = selv;             // col o == l

    // rotate prefetched state
    p = pn; iv = iv_n; qpv = qpv_n;
    cp0 = cpn0; cp1 = cpn1; cp2 = cpn2;
    px = pxn; py = pyn; pz = pzn;
    ka0 = kan0; ka1 = kan1; va0 = van0; va1 = van1;
  }
  __syncthreads();

  // coalesced transposed store: out[b][o][m0+pt]
  int o0 = tid >> 5, pt = tid & 31;
  int m0 = pbase & (M_-1);
  long outb = ((long)b*64) * M_ + m0 + pt;
  #pragma unroll
  for (int ii=0; ii<8; ii++){
    int o = o0*8 + ii;
    out[outb + (long)o*M_] = s_tile[pt*66 + o];
  }
}

extern "C" void kernel_launch(void* const* d_in, const int* in_sizes, int n_in,
                              void* d_out, int out_size, void* d_ws, size_t ws_size,
                              hipStream_t stream) {
  const float* center_pos = (const float*)d_in[0];
  const float* center_fea = (const float*)d_in[1];
  const float* pos        = (const float*)d_in[2];
  const float* fea        = (const float*)d_in[3];
  const int*   idx        = (const int*)d_in[4];
  const float* Wq = (const float*)d_in[5];   const float* bq = (const float*)d_in[6];
  const float* Wk = (const float*)d_in[7];   const float* bk = (const float*)d_in[8];
  const float* Wv = (const float*)d_in[9];   const float* bv = (const float*)d_in[10];
  const float* cpe_w1 = (const float*)d_in[11]; const float* cpe_s = (const float*)d_in[12];
  const float* cpe_b  = (const float*)d_in[13]; const float* cpe_w2 = (const float*)d_in[14];
  const float* cpe_b2 = (const float*)d_in[15];
  const float* pe_w1 = (const float*)d_in[16]; const float* pe_s = (const float*)d_in[17];
  const float* pe_b  = (const float*)d_in[18]; const float* pe_w2 = (const float*)d_in[19];
  const float* pe_b2 = (const float*)d_in[20];
  const float* we_w1 = (const float*)d_in[21]; const float* we_s = (const float*)d_in[22];
  const float* we_b  = (const float*)d_in[23]; const float* we_w2 = (const float*)d_in[24];
  const float* we_b2 = (const float*)d_in[25];

  // workspace: xk bf16 8.4MB | xv bf16 8.4MB | qw f32 2.1MB
  const size_t SZ = (size_t)B_*N_*64;
  u16* xk = (u16*)d_ws;
  u16* xv = xk + SZ;
  float* qwp = (float*)(xv + SZ);
  float* outp = (float*)d_out;

  hipLaunchKernelGGL(pre_kernel, dim3(512), dim3(256), 0, stream,
      center_pos, center_fea, fea, Wq, bq, Wk, bk, Wv, bv,
      cpe_w1, cpe_s, cpe_b, cpe_w2, cpe_b2, we_w1, xk, xv, qwp);
  hipLaunchKernelGGL(attn_kernel, dim3(2048), dim3(256), 0, stream,
      center_pos, pos, idx, pe_w1, pe_s, pe_b, pe_w2, pe_b2,
      we_w1, we_s, we_b, we_w2, we_b2, xk, xv, qwp, outp);
}